// Round 10
// baseline (624.163 us; speedup 1.0000x reference)
//
#include <hip/hip_runtime.h>
#include <math.h>

// ---------------------------------------------------------------------------
// Encoder block on MI355X (gfx950).  B=4, T=2048, E=1024, H=16, Dh=64, FF=4096.
// Inputs may be bf16 or fp32 (harness-dependent, detector-classified).
// GEMM v8: hedged T4 upgrade.
//  - QKV / Wo / W2: gemm3buf 256x128 BK=64, TRIPLE-buffered LDS (144KB) with
//    counted vmcnt: stage tile t+2 at iter t; barrier waits only vmcnt(6)
//    (= tile t+1's loads, issued a full iter earlier -> 2-iter latency slack).
//    Never vmcnt(0) in the main loop (T4, m218: counted-vs-drain = +38-73%).
//    All our GEMMs are 1 blk/CU -> no cross-block overlap; the 2-phase
//    barrier drained THIS-iter loads (m233 stall).  Sync trace verified:
//    FIFO vmcnt retirement => tile t+1 landed at each barrier; lgkmcnt(0)
//    closes cross-wave LDS-read WAR; sched_barrier(0) pins ds_read hoisting.
//  - W1 stays gemm2ph<2,256> (117us measured) as in-run control.
// Attention v9: transposed flash, (256,3), setprio, swizzled Ps.
// ---------------------------------------------------------------------------

using u16 = unsigned short;
typedef __bf16 bf16x8 __attribute__((ext_vector_type(8)));
typedef __bf16 bf16x4 __attribute__((ext_vector_type(4)));
typedef unsigned short u16x8 __attribute__((ext_vector_type(8)));
typedef unsigned short u16x4 __attribute__((ext_vector_type(4)));
typedef float f32x4 __attribute__((ext_vector_type(4)));

#if defined(__has_builtin)
#if __has_builtin(__builtin_amdgcn_exp2f)
#define EXP2F(x) __builtin_amdgcn_exp2f(x)
#endif
#endif
#ifndef EXP2F
#define EXP2F(x) __expf((x) * 0.69314718055994531f)
#endif

__device__ __forceinline__ float bf2f(u16 h) {
  return __uint_as_float(((unsigned int)h) << 16);
}
__device__ __forceinline__ u16 f2bf(float f) {  // RNE
  unsigned int u = __float_as_uint(f);
  u += 0x7fffu + ((u >> 16) & 1u);
  return (u16)(u >> 16);
}

__device__ __forceinline__ void gload_lds16(const void* g, void* l) {
  __builtin_amdgcn_global_load_lds(
      (__attribute__((address_space(1))) void*)(g),
      (__attribute__((address_space(3))) void*)(l), 16, 0, 0);
}

// ---------------------------------------------------------------------------
// Dtype detector (flag=1 -> fp32 inputs).
// ---------------------------------------------------------------------------
__global__ __launch_bounds__(256) void detect_dtype(const u16* __restrict__ x,
                                                    int* __restrict__ flag) {
  __shared__ int cnt[256];
  int c = 0;
#pragma unroll
  for (int j = 0; j < 8; ++j) {
    float v = bf2f(x[threadIdx.x * 8 + j]);
    float a = fabsf(v);
    if (a >= 1e-4f && a <= 64.0f) ++c;
  }
  cnt[threadIdx.x] = c;
  __syncthreads();
  if (threadIdx.x == 0) {
    int t = 0;
    for (int i = 0; i < 256; ++i) t += cnt[i];
    flag[0] = (t < 1638) ? 1 : 0;
  }
}

__global__ __launch_bounds__(256) void cvt_copy(const void* __restrict__ in,
                                                u16* __restrict__ out,
                                                const int* __restrict__ flagp,
                                                long n) {
  long idx = ((long)blockIdx.x * 256 + threadIdx.x) * 4;
  if (idx >= n) return;
  if (*flagp) {
    float4 v = *(const float4*)((const float*)in + idx);
    out[idx] = f2bf(v.x); out[idx + 1] = f2bf(v.y);
    out[idx + 2] = f2bf(v.z); out[idx + 3] = f2bf(v.w);
  } else {
    *(u16x4*)(out + idx) = *(const u16x4*)((const u16*)in + idx);
  }
}

__global__ __launch_bounds__(256) void cvt_vecs(
    const void* s0, const void* s1, const void* s2, const void* s3,
    const void* s4, const void* s5, const void* s6, u16* __restrict__ dst,
    const int* __restrict__ flagp) {
  const int lens[7] = {1024, 1024, 1024, 4096, 1024, 1024, 1024};
  const int offs[7] = {0, 1024, 2048, 3072, 7168, 8192, 9216};
  const void* srcs[7] = {s0, s1, s2, s3, s4, s5, s6};
  int w = blockIdx.x;
  int f = *flagp;
  for (int i = threadIdx.x; i < lens[w]; i += 256)
    dst[offs[w] + i] = f ? f2bf(((const float*)srcs[w])[i])
                         : ((const u16*)srcs[w])[i];
}

// ---------------------------------------------------------------------------
// Batched transpose + convert: out[b][c*R+r] = cvt(in[b][r*C+c]).
// ---------------------------------------------------------------------------
__global__ __launch_bounds__(256) void transpose_cvt(
    const void* __restrict__ in, u16* __restrict__ out, int R, int C,
    long inBS, long outBS, const int* __restrict__ flagp) {
  __shared__ u16 tile[32][33];
  int f = *flagp;
  u16* ob = out + (long)blockIdx.z * outBS;
  int c = blockIdx.x * 32 + threadIdx.x;
  int r0 = blockIdx.y * 32;
  if (f) {
    const float* ib = (const float*)in + (long)blockIdx.z * inBS;
#pragma unroll
    for (int i = threadIdx.y; i < 32; i += 8)
      tile[i][threadIdx.x] = f2bf(ib[(long)(r0 + i) * C + c]);
  } else {
    const u16* ib = (const u16*)in + (long)blockIdx.z * inBS;
#pragma unroll
    for (int i = threadIdx.y; i < 32; i += 8)
      tile[i][threadIdx.x] = ib[(long)(r0 + i) * C + c];
  }
  __syncthreads();
  int r = r0 + threadIdx.x;
  int c0 = blockIdx.x * 32;
#pragma unroll
  for (int i = threadIdx.y; i < 32; i += 8)
    ob[(long)(c0 + i) * R + r] = tile[threadIdx.x][i];
}

// ---------------------------------------------------------------------------
// Pre-swizzle K and V into MFMA fragment order.
// ---------------------------------------------------------------------------
__global__ __launch_bounds__(256) void kv_frag(const u16* __restrict__ qkv,
                                               u16* __restrict__ KF,
                                               u16* __restrict__ VF) {
  __shared__ u16 Kt[64][72];
  __shared__ u16 Vt[64][72];
  const int jblk = blockIdx.x, bh = blockIdx.y;
  const int b = bh >> 4, h = bh & 15;
  const int tid = threadIdx.x;
  const long j0 = jblk * 64;

  {
    int tt = tid >> 2, c0 = (tid & 3) * 16;
    const u16* src = qkv + (long)(b * 2048 + j0 + tt) * 3072 + h * 64 + c0;
    *(u16x8*)(&Kt[tt][c0]) = *(const u16x8*)(src + 1024);
    *(u16x8*)(&Kt[tt][c0 + 8]) = *(const u16x8*)(src + 1024 + 8);
    *(u16x8*)(&Vt[tt][c0]) = *(const u16x8*)(src + 2048);
    *(u16x8*)(&Vt[tt][c0 + 8]) = *(const u16x8*)(src + 2048 + 8);
  }
  __syncthreads();

  long obase = ((long)bh * 32 + jblk) * 8 * 512;
#pragma unroll
  for (int si = 0; si < 2; ++si) {
    int s = tid * 2 + si;
    int f = s >> 6, ln = s & 63;
    int kt = f >> 2, nt = f & 3;
    int lr = ln & 15, lq = ln >> 4;
    u16x8 ko, vo;
#pragma unroll
    for (int j = 0; j < 8; ++j) {
      ko[j] = Kt[nt * 16 + lr][kt * 32 + lq * 8 + j];
      vo[j] = Vt[kt * 32 + lq * 8 + j][nt * 16 + lr];
    }
    *(u16x8*)(KF + obase + (long)s * 8) = ko;
    *(u16x8*)(VF + obase + (long)s * 8) = vo;
  }
}

// ---------------------------------------------------------------------------
// Shared fragment read: LDS(row,slot) holds global chunk slot^(row&7);
// read undoes the XOR (0 conflicts, verified r2/r4/r8).
// ---------------------------------------------------------------------------
__device__ __forceinline__ bf16x8 fragld64(const u16* lb, int row, int ks,
                                           int lq) {
  int slot = ((ks << 2) | lq) ^ (row & 7);
  return *(const bf16x8*)(lb + row * 64 + slot * 8);
}

// ---------------------------------------------------------------------------
// gemm2ph: 256xBN, BK=64, 2-phase dbuf, one __syncthreads per K-tile.
// (kept for W1 as the measured-best control: 117us @ BN=256)
// ---------------------------------------------------------------------------
template <int EPI, int BN>
__global__ __launch_bounds__(512, 2) void gemm2ph(
    const u16* __restrict__ A, const u16* __restrict__ Bt,
    const u16* __restrict__ bias, u16* __restrict__ Cout,
    int M, int N, int K) {
  static_assert(BN == 256 || BN == 128, "");
  constexpr int NFQ = BN / 128;  // B fragments per quadrant
  __shared__ u16 As[2][16384];
  __shared__ u16 Bs[2][BN * 64];
  const int tid = threadIdx.x;
  const int wave = tid >> 6, lane = tid & 63;
  const int lr = lane & 15, lq = lane >> 4;

  const int MT = M >> 8, NTt = N / BN;
  const int nwg = MT * NTt;
  int wg = blockIdx.x;
  if (!(nwg & 7)) wg = (wg & 7) * (nwg >> 3) + (wg >> 3);  // XCD swizzle
  const int tm = wg % MT, tn = wg / MT;
  const long m0 = (long)tm << 8;
  const long n0 = (long)tn * BN;

  const int wm = (wave >> 2) << 7;       // 0 / 128
  const int wn = (wave & 3) * (BN / 4);  // per-wave N offset

  const int srow = lane >> 3;
  const int skoff = ((lane & 7) ^ srow) * 8;  // pre-swizzled global source

  auto stage = [&](int buf, int t) {
#pragma unroll
    for (int j = 0; j < 4; ++j)
      gload_lds16(
          A + (m0 + j * 64 + wave * 8 + srow) * (long)K + t * 64 + skoff,
          &As[buf][j * 4096 + (wave << 9)]);
#pragma unroll
    for (int j = 0; j < BN / 64; ++j)
      gload_lds16(
          Bt + (n0 + j * 64 + wave * 8 + srow) * (long)K + t * 64 + skoff,
          &Bs[buf][j * 4096 + (wave << 9)]);
  };

  f32x4 acc[8][2 * NFQ] = {};
  const int NT = K >> 6;
  int cur = 0;

  stage(0, 0);
  __syncthreads();

  for (int t = 0; t < NT; ++t) {
    const u16* Ab = As[cur];
    const u16* Bb = Bs[cur];
    if (t + 1 < NT) stage(cur ^ 1, t + 1);  // prefetch overlaps compute

    bf16x8 a_[4][2], b0_[NFQ][2], b1_[NFQ][2];
    // quadrant (m-lo, n-lo)
#pragma unroll
    for (int mf = 0; mf < 4; ++mf)
#pragma unroll
      for (int ks = 0; ks < 2; ++ks)
        a_[mf][ks] = fragld64(Ab, wm + mf * 16 + lr, ks, lq);
#pragma unroll
    for (int nf = 0; nf < NFQ; ++nf)
#pragma unroll
      for (int ks = 0; ks < 2; ++ks)
        b0_[nf][ks] = fragld64(Bb, wn + nf * 16 + lr, ks, lq);
#pragma unroll
    for (int mf = 0; mf < 4; ++mf)
#pragma unroll
      for (int nf = 0; nf < NFQ; ++nf)
#pragma unroll
        for (int ks = 0; ks < 2; ++ks)
          acc[mf][nf] = __builtin_amdgcn_mfma_f32_16x16x32_bf16(
              a_[mf][ks], b0_[nf][ks], acc[mf][nf], 0, 0, 0);
    // quadrant (m-lo, n-hi)
#pragma unroll
    for (int nf = 0; nf < NFQ; ++nf)
#pragma unroll
      for (int ks = 0; ks < 2; ++ks)
        b1_[nf][ks] = fragld64(Bb, wn + BN / 8 + nf * 16 + lr, ks, lq);
#pragma unroll
    for (int mf = 0; mf < 4; ++mf)
#pragma unroll
      for (int nf = 0; nf < NFQ; ++nf)
#pragma unroll
        for (int ks = 0; ks < 2; ++ks)
          acc[mf][NFQ + nf] = __builtin_amdgcn_mfma_f32_16x16x32_bf16(
              a_[mf][ks], b1_[nf][ks], acc[mf][NFQ + nf], 0, 0, 0);
    // quadrant (m-hi, n-hi)
#pragma unroll
    for (int mf = 0; mf < 4; ++mf)
#pragma unroll
      for (int ks = 0; ks < 2; ++ks)
        a_[mf][ks] = fragld64(Ab, wm + 64 + mf * 16 + lr, ks, lq);
#pragma unroll
    for (int mf = 0; mf < 4; ++mf)
#pragma unroll
      for (int nf = 0; nf < NFQ; ++nf)
#pragma unroll
        for (int ks = 0; ks < 2; ++ks)
          acc[4 + mf][NFQ + nf] = __builtin_amdgcn_mfma_f32_16x16x32_bf16(
              a_[mf][ks], b1_[nf][ks], acc[4 + mf][NFQ + nf], 0, 0, 0);
    // quadrant (m-hi, n-lo)
#pragma unroll
    for (int mf = 0; mf < 4; ++mf)
#pragma unroll
      for (int nf = 0; nf < NFQ; ++nf)
#pragma unroll
        for (int ks = 0; ks < 2; ++ks)
          acc[4 + mf][nf] = __builtin_amdgcn_mfma_f32_16x16x32_bf16(
              a_[mf][ks], b0_[nf][ks], acc[4 + mf][nf], 0, 0, 0);

    __syncthreads();
    cur ^= 1;
  }

  const int rq = lq * 4;
#pragma unroll
  for (int mf = 0; mf < 8; ++mf)
#pragma unroll
    for (int nf2 = 0; nf2 < 2 * NFQ; ++nf2) {
      const int col = (int)n0 + wn + nf2 * 16 + lr;
#pragma unroll
      for (int r = 0; r < 4; ++r) {
        const long row = m0 + wm + mf * 16 + rq + r;
        float v = acc[mf][nf2][r];
        if (EPI == 2) {
          v += bf2f(bias[col]);
          v = 0.5f * v * (1.0f + erff(v * 0.70710678118654752f));
        } else if (EPI == 3) {
          v += bf2f(bias[col]);
        }
        Cout[row * (long)N + col] = f2bf(v);
      }
    }
}

// ---------------------------------------------------------------------------
// gemm3buf: 256x128 tile, BK=64, 512 thr, TRIPLE-buffered LDS (144KB) with
// counted vmcnt(6) at the barrier (T4).  Sync trace (NT=4, verified):
// prologue stages t0,t1 (12 out), vmcnt(6) -> t0 landed.  iter t: stage
// t+2 (6 out added); reads buf[t]; MFMA; vmcnt(6) -> oldest-retire means
// tile t+1's 6 loads (issued iter t-1) are done; lgkmcnt(0) closes the
// cross-wave LDS-read WAR; barrier.  Tail: no stage -> vmcnt(0).
// ---------------------------------------------------------------------------
template <int EPI>
__global__ __launch_bounds__(512, 2) void gemm3buf(
    const u16* __restrict__ A, const u16* __restrict__ Bt,
    const u16* __restrict__ bias, u16* __restrict__ Cout,
    int M, int N, int K) {
  __shared__ u16 As[3][16384];  // 96KB
  __shared__ u16 Bs[3][8192];   // 48KB
  const int tid = threadIdx.x;
  const int wave = tid >> 6, lane = tid & 63;
  const int lr = lane & 15, lq = lane >> 4;

  const int MT = M >> 8, NTt = N >> 7;
  const int nwg = MT * NTt;
  int wg = blockIdx.x;
  if (!(nwg & 7)) wg = (wg & 7) * (nwg >> 3) + (wg >> 3);  // XCD swizzle
  const int tm = wg % MT, tn = wg / MT;
  const long m0 = (long)tm << 8;
  const long n0 = (long)tn << 7;

  const int wm = (wave >> 2) << 7;  // 0 / 128
  const int wn = (wave & 3) * 32;   // per-wave N offset (128/4)

  const int srow = lane >> 3;
  const int skoff = ((lane & 7) ^ srow) * 8;  // pre-swizzled global source

  auto stage = [&](u16* ab, u16* bb, int t) {
#pragma unroll
    for (int j = 0; j < 4; ++j)
      gload_lds16(
          A + (m0 + j * 64 + wave * 8 + srow) * (long)K + t * 64 + skoff,
          ab + j * 4096 + (wave << 9));
#pragma unroll
    for (int j = 0; j < 2; ++j)
      gload_lds16(
          Bt + (n0 + j * 64 + wave * 8 + srow) * (long)K + t * 64 + skoff,
          bb + j * 4096 + (wave << 9));
  };

  u16 *pa0 = &As[0][0], *pa1 = &As[1][0], *pa2 = &As[2][0];
  u16 *pb0 = &Bs[0][0], *pb1 = &Bs[1][0], *pb2 = &Bs[2][0];

  f32x4 acc[8][2] = {};
  const int NT = K >> 6;

  stage(pa0, pb0, 0);
  stage(pa1, pb1, 1);
  asm volatile("s_waitcnt vmcnt(6)" ::: "memory");  // tile 0 landed
  __builtin_amdgcn_s_barrier();
  __builtin_amdgcn_sched_barrier(0);

  for (int t = 0; t < NT; ++t) {
    const bool pf = (t + 2 < NT);
    if (pf) stage(pa2, pb2, t + 2);  // stays in flight across the barrier

    bf16x8 a_[4][2], b0_[2], b1_[2];
    // quadrant (m-lo, n-lo)
#pragma unroll
    for (int mf = 0; mf < 4; ++mf)
#pragma unroll
      for (int ks = 0; ks < 2; ++ks)
        a_[mf][ks] = fragld64(pa0, wm + mf * 16 + lr, ks, lq);
#pragma unroll
    for (int ks = 0; ks < 2; ++ks) b0_[ks] = fragld64(pb0, wn + lr, ks, lq);
#pragma unroll
    for (int mf = 0; mf < 4; ++mf)
#pragma unroll
      for (int ks = 0; ks < 2; ++ks)
        acc[mf][0] = __builtin_amdgcn_mfma_f32_16x16x32_bf16(
            a_[mf][ks], b0_[ks], acc[mf][0], 0, 0, 0);
    // quadrant (m-lo, n-hi)
#pragma unroll
    for (int ks = 0; ks < 2; ++ks)
      b1_[ks] = fragld64(pb0, wn + 16 + lr, ks, lq);
#pragma unroll
    for (int mf = 0; mf < 4; ++mf)
#pragma unroll
      for (int ks = 0; ks < 2; ++ks)
        acc[mf][1] = __builtin_amdgcn_mfma_f32_16x16x32_bf16(
            a_[mf][ks], b1_[ks], acc[mf][1], 0, 0, 0);
    // quadrant (m-hi, n-hi)
#pragma unroll
    for (int mf = 0; mf < 4; ++mf)
#pragma unroll
      for (int ks = 0; ks < 2; ++ks)
        a_[mf][ks] = fragld64(pa0, wm + 64 + mf * 16 + lr, ks, lq);
#pragma unroll
    for (int mf = 0; mf < 4; ++mf)
#pragma unroll
      for (int ks = 0; ks < 2; ++ks)
        acc[4 + mf][1] = __builtin_amdgcn_mfma_f32_16x16x32_bf16(
            a_[mf][ks], b1_[ks], acc[4 + mf][1], 0, 0, 0);
    // quadrant (m-hi, n-lo)
#pragma unroll
    for (int mf = 0; mf < 4; ++mf)
#pragma unroll
      for (int ks = 0; ks < 2; ++ks)
        acc[4 + mf][0] = __builtin_amdgcn_mfma_f32_16x16x32_bf16(
            a_[mf][ks], b0_[ks], acc[4 + mf][0], 0, 0, 0);

    if (pf)
      asm volatile("s_waitcnt vmcnt(6) lgkmcnt(0)" ::: "memory");
    else
      asm volatile("s_waitcnt vmcnt(0) lgkmcnt(0)" ::: "memory");
    __builtin_amdgcn_s_barrier();
    __builtin_amdgcn_sched_barrier(0);

    u16* ta = pa0; pa0 = pa1; pa1 = pa2; pa2 = ta;
    u16* tb = pb0; pb0 = pb1; pb1 = pb2; pb2 = tb;
  }

  const int rq = lq * 4;
#pragma unroll
  for (int mf = 0; mf < 8; ++mf)
#pragma unroll
    for (int nf2 = 0; nf2 < 2; ++nf2) {
      const int col = (int)n0 + wn + nf2 * 16 + lr;
#pragma unroll
      for (int r = 0; r < 4; ++r) {
        const long row = m0 + wm + mf * 16 + rq + r;
        float v = acc[mf][nf2][r];
        if (EPI == 2) {
          v += bf2f(bias[col]);
          v = 0.5f * v * (1.0f + erff(v * 0.70710678118654752f));
        } else if (EPI == 3) {
          v += bf2f(bias[col]);
        }
        Cout[row * (long)N + col] = f2bf(v);
      }
    }
}

// ---------------------------------------------------------------------------
// Flash attention v9.  Grid (T/128, B*H), block 256, (256,3): 3 blocks/CU.
// Each wave: 32 Q-rows.  S^T = K.Q^T via mfma(bk, aq) -> per-lane softmax.
// Ps: 32 rows x 64 u16, 16B-window XOR swizzle (wphys = wlog ^ (lr&7)).
// ---------------------------------------------------------------------------
__global__ __launch_bounds__(256, 3) void flash_attn(
    const u16* __restrict__ qkv, const u16* __restrict__ KF,
    const u16* __restrict__ VF, u16* __restrict__ cat) {
  const int T = 2048, LD = 3072;
  const float QSCALE = 0.18033688011112042f;  // log2e / 8
  const float EXPC = 4.3280851226677321f;     // 3 * log2e (static max)
  const int bh = blockIdx.y;
  const int b = bh >> 4, h = bh & 15;
  const int tid = threadIdx.x, wave = tid >> 6, lane = tid & 63;
  const int lr = lane & 15, lq = lane >> 4;

  __shared__ u16 Ps[4 * 32 * 64];  // per-wave 32 rows x 64 u16, swizzled
  u16* Pw = Ps + wave * 32 * 64;

  const u16* Qb = qkv + (long)(b * 2048) * LD + h * 64;
  const long fbase = (long)bh * 32 * 8 * 512;

  bf16x8 aq[2][2];
#pragma unroll
  for (int st = 0; st < 2; ++st) {
    int qrow = blockIdx.x * 128 + wave * 32 + st * 16 + lr;
#pragma unroll
    for (int kt = 0; kt < 2; ++kt) {
      u16x8 q = *(const u16x8*)(Qb + (long)qrow * LD + kt * 32 + lq * 8);
      bf16x8 t;
#pragma unroll
      for (int j = 0; j < 8; ++j) t[j] = (__bf16)(bf2f(q[j]) * QSCALE);
      aq[st][kt] = t;
    }
  }

  f32x4 o[2][4] = {};
  float lsum[2] = {0.0f, 0.0f};

  for (int jblk = 0; jblk < T / 64; ++jblk) {
    const u16* kf = KF + fbase + (long)jblk * 8 * 512;
    const u16* vf = VF + fbase + (long)jblk * 8 * 512;

    bf16x8 bk[2][4];
#pragma unroll
    for (int kt = 0; kt < 2; ++kt)
#pragma unroll
      for (int nt = 0; nt < 4; ++nt)
        bk[kt][nt] = *(const bf16x8*)(kf + (kt * 4 + nt) * 512 + lane * 8);

    f32x4 s[2][4] = {};
    __builtin_amdgcn_s_setprio(1);
#pragma unroll
    for (int st = 0; st < 2; ++st)
#pragma unroll
      for (int nt = 0; nt < 4; ++nt)
#pragma unroll
        for (int kt = 0; kt < 2; ++kt)
          s[st][nt] = __builtin_amdgcn_mfma_f32_16x16x32_bf16(
              bk[kt][nt], aq[st][kt], s[st][nt], 0, 0, 0);
    __builtin_amdgcn_s_setprio(0);

    bf16x8 bv[2][4];
#pragma unroll
    for (int kt = 0; kt < 2; ++kt)
#pragma unroll
      for (int nt = 0; nt < 4; ++nt)
        bv[kt][nt] = *(const bf16x8*)(vf + (kt * 4 + nt) * 512 + lane * 8);

#pragma unroll
    for (int st = 0; st < 2; ++st)
#pragma unroll
      for (int nt = 0; nt < 4; ++nt) {
        f32x4 p;
#pragma unroll
        for (int r = 0; r < 4; ++r) p[r] = EXP2F(s[st][nt][r] - EXPC);
        lsum[st] += (p[0] + p[1]) + (p[2] + p[3]);
        bf16x4 pk;
#pragma unroll
        for (int r = 0; r < 4; ++r) pk[r] = (__bf16)p[r];
        int wph = (nt * 2 + (lq >> 1)) ^ (lr & 7);
        *(bf16x4*)(Pw + (st * 16 + lr) * 64 + wph * 8 + (lq & 1) * 4) = pk;
      }

#pragma unroll
    for (int st = 0; st < 2; ++st)
#pragma unroll
      for (int kt = 0; kt < 2; ++kt) {
        bf16x8 ap = *(const bf16x8*)(
            Pw + (st * 16 + lr) * 64 + (((kt * 4 + lq) ^ (lr & 7)) * 8));
        __builtin_amdgcn_s_setprio(1);
#pragma unroll
        for (int nt = 0; nt < 4; ++nt)
          o[st][nt] = __builtin_amdgcn_mfma_f32_16x16x32_bf16(
              ap, bv[kt][nt], o[st][nt], 0, 0, 0);
        __builtin_amdgcn_s_setprio(0);
      }
  }

#pragma unroll
  for (int st = 0; st < 2; ++st) {
    lsum[st] += __shfl_xor(lsum[st], 16, 64);
    lsum[st] += __shfl_xor(lsum[st], 32, 64);
  }

  u16* ob = cat + (long)(b * 2048) * 1024 + h * 64;
#pragma unroll
  for (int st = 0; st < 2; ++st) {
    int trow = blockIdx.x * 128 + wave * 32 + st * 16 + lq * 4;
#pragma unroll
    for (int r = 0; r < 4; ++r) {
      float linv = 1.0f / __shfl(lsum[st], lq * 4 + r, 64);
#pragma unroll
      for (int nt = 0; nt < 4; ++nt)
        ob[(long)(trow + r) * 1024 + nt * 16 + lr] = f2bf(o[st][nt][r] * linv);
    }
  }
}

// ---------------------------------------------------------------------------
// out[row] = res[row] + LN(y[row]) * g + b.   y is bf16.
// ---------------------------------------------------------------------------
__global__ __launch_bounds__(256) void ln_residual(
    const u16* __restrict__ y, const void* __restrict__ res, int res_raw,
    const u16* __restrict__ g, const u16* __restrict__ bb,
    void* __restrict__ out, const int* __restrict__ flagp, int final_out) {
  const long row = blockIdx.x;
  const int tid = threadIdx.x, wave = tid >> 6, lane = tid & 63;
  u16x4 yv = *(const u16x4*)(y + row * 1024 + tid * 4);
  float yy[4];
#pragma unroll
  for (int j = 0; j < 4; ++j) yy[j] = bf2f(yv[j]);
  float s1 = yy[0] + yy[1] + yy[2] + yy[3];
  float s2 = yy[0] * yy[0] + yy[1] * yy[1] + yy[2] * yy[2] + yy[3] * yy[3];
#pragma unroll
  for (int off = 1; off < 64; off <<= 1) {
    s1 += __shfl_xor(s1, off, 64);
    s2 += __shfl_xor(s2, off, 64);
  }
  __shared__ float ws1[4], ws2[4];
  if (lane == 0) { ws1[wave] = s1; ws2[wave] = s2; }
  __syncthreads();
  float t1 = ws1[0] + ws1[1] + ws1[2] + ws1[3];
  float t2 = ws2[0] + ws2[1] + ws2[2] + ws2[3];
  float mu = t1 * (1.0f / 1024.0f);
  float var = t2 * (1.0f / 1024.0f) - mu * mu;
  float rstd = rsqrtf(var + 1e-5f);
  int i = tid * 4;
  bool f32in = res_raw && (*flagp);
  bool f32out = final_out && (*flagp);
#pragma unroll
  for (int j = 0; j < 4; ++j) {
    float rv = f32in ? ((const float*)res)[row * 1024 + i + j]
                     : bf2f(((const u16*)res)[row * 1024 + i + j]);
    float o = rv + (yy[j] - mu) * rstd * bf2f(g[i + j]) + bf2f(bb[i + j]);
    if (f32out)
      ((float*)out)[row * 1024 + i + j] = o;
    else
      ((u16*)out)[row * 1024 + i + j] = f2bf(o);
  }
}

// ---------------------------------------------------------------------------
extern "C" void kernel_launch(void* const* d_in, const int* in_sizes, int n_in,
                              void* d_out, int out_size, void* d_ws,
                              size_t ws_size, hipStream_t stream) {
  const void* x_raw = d_in[0];
  const void* Wq = d_in[1];
  const void* Wk = d_in[2];
  const void* Wv = d_in[3];
  const void* Wo = d_in[4];
  const void* bo = d_in[5];
  const void* ln1g = d_in[6];
  const void* ln1b = d_in[7];
  const void* W1 = d_in[8];
  const void* b1 = d_in[9];
  const void* W2 = d_in[10];
  const void* b2 = d_in[11];
  const void* ln2g = d_in[12];
  const void* ln2b = d_in[13];

  char* ws = (char*)d_ws;
  u16* qkv = (u16*)(ws + 0);              // [8192,3072]
  u16* mha = (u16*)(ws + 0);              // [8192,1024] bf16
  u16* h1 = (u16*)(ws + 0);               // [8192,4096] bf16
  u16* cat = (u16*)(ws + 50331648);       // [8192,1024]
  u16* KF = (u16*)(ws + 67108864);        // frag-order K (16M)
  u16* ff = (u16*)(ws + 67108864);        // [8192,1024] bf16
  u16* xb = (u16*)(ws + 83886080);        // bf16 x
  u16* VF = (u16*)(ws + 83886080);        // frag-order V (16M)
  u16* x1 = (u16*)(ws + 83886080);        // [8192,1024] after flash
  u16* wqkvt = (u16*)(ws + 100663296);    // [3072,1024]
  u16* wot = (u16*)(ws + 106954752);      // [1024,1024]
  u16* w1t = (u16*)(ws + 109051904);      // [4096,1024]
  u16* w2t = (u16*)(ws + 117440512);      // [1024,4096]
  u16* vecs = (u16*)(ws + 125829120);     // packed bias/gain vectors
  int* flag = (int*)(ws + 125853696);     // dtype flag (1 = fp32)

  const u16* v_bo = vecs + 0;
  const u16* v_l1g = vecs + 1024;
  const u16* v_l1b = vecs + 2048;
  const u16* v_b1 = vecs + 3072;
  const u16* v_b2 = vecs + 7168;
  const u16* v_l2g = vecs + 8192;
  const u16* v_l2b = vecs + 9216;

  detect_dtype<<<1, 256, 0, stream>>>((const u16*)x_raw, flag);
  cvt_copy<<<8192, 256, 0, stream>>>(x_raw, xb, flag, 8388608L);
  cvt_vecs<<<7, 256, 0, stream>>>(bo, ln1g, ln1b, b1, b2, ln2g, ln2b, vecs, flag);

  dim3 tb(32, 8);
  transpose_cvt<<<dim3(2, 32, 16), tb, 0, stream>>>(Wq, wqkvt, 1024, 64, 65536, 65536, flag);
  transpose_cvt<<<dim3(2, 32, 16), tb, 0, stream>>>(Wk, wqkvt + 1048576, 1024, 64, 65536, 65536, flag);
  transpose_cvt<<<dim3(2, 32, 16), tb, 0, stream>>>(Wv, wqkvt + 2097152, 1024, 64, 65536, 65536, flag);
  transpose_cvt<<<dim3(32, 32, 1), tb, 0, stream>>>(Wo, wot, 1024, 1024, 0, 0, flag);
  transpose_cvt<<<dim3(128, 32, 1), tb, 0, stream>>>(W1, w1t, 1024, 4096, 0, 0, flag);
  transpose_cvt<<<dim3(32, 128, 1), tb, 0, stream>>>(W2, w2t, 4096, 1024, 0, 0, flag);

  // qkv = xb @ Wqkv   (gemm3buf triple-buffer; 768 wgs = 3 even rounds)
  gemm3buf<0><<<768, 512, 0, stream>>>(xb, wqkvt, nullptr, qkv, 8192, 3072, 1024);
  // K/V -> MFMA fragment order
  kv_frag<<<dim3(32, 64), 256, 0, stream>>>(qkv, KF, VF);
  // cat = attention
  flash_attn<<<dim3(16, 64), 256, 0, stream>>>(qkv, KF, VF, cat);
  // mha = cat @ Wo + bo (gemm3buf; grid 256)
  gemm3buf<3><<<256, 512, 0, stream>>>(cat, wot, v_bo, mha, 8192, 1024, 1024);
  // x1 = x_raw + LN(mha)
  ln_residual<<<8192, 256, 0, stream>>>(mha, x_raw, 1, v_l1g, v_l1b, x1, flag, 0);
  // h1 = gelu(x1 @ W1 + b1) (gemm2ph BN=256 control; 512 wgs, 117us measured)
  gemm2ph<2, 256><<<512, 512, 0, stream>>>(x1, w1t, v_b1, h1, 8192, 4096, 1024);
  // ff = h1 @ W2 + b2 (gemm3buf, K=4096 = 64 iters, most barrier-bound)
  gemm3buf<3><<<256, 512, 0, stream>>>(h1, w2t, v_b2, ff, 8192, 1024, 4096);
  // out = x1 + LN(ff)
  ln_residual<<<8192, 256, 0, stream>>>(ff, x1, 0, v_l2g, v_l2b, d_out, flag, 1);
}

// Round 11
// 617.807 us; speedup vs baseline: 1.0103x; 1.0103x over previous
//
#include <hip/hip_runtime.h>
#include <math.h>

// ---------------------------------------------------------------------------
// Encoder block on MI355X (gfx950).  B=4, T=2048, E=1024, H=16, Dh=64, FF=4096.
// Inputs may be bf16 or fp32 (harness-dependent, detector-classified).
// GEMM v7 (r9 measured-best, 621.9us): gemm2ph everywhere.
//   QKV <0,128> 768 wgs | Wo <3,128> 256 | W1 <2,256> 512 | W2 <3,128> 256.
//   BK=64, 2-phase dbuf, XOR-swz (0 conflicts), XCD swizzle.
//   STRUCTURAL CEILING (r10 concluded): W1 at 587 TF = 90% of the 2-phase
//   ceiling (m248: ~650 TF @K=1024).  Counted-vmcnt triple-buffer (r10) and
//   occupancy levers (r5/r6) both null -> stall is the schedule itself; the
//   8-phase escape needs the exact m201 artifact (2 failed reconstructions).
// Attention v9: transposed flash, (256,3), setprio, swizzled Ps (654 TF).
// Setup: Wq/Wk/Wv transposes merged into ONE z=48 launch (-2 launches).
// ---------------------------------------------------------------------------

using u16 = unsigned short;
typedef __bf16 bf16x8 __attribute__((ext_vector_type(8)));
typedef __bf16 bf16x4 __attribute__((ext_vector_type(4)));
typedef unsigned short u16x8 __attribute__((ext_vector_type(8)));
typedef unsigned short u16x4 __attribute__((ext_vector_type(4)));
typedef float f32x4 __attribute__((ext_vector_type(4)));

#if defined(__has_builtin)
#if __has_builtin(__builtin_amdgcn_exp2f)
#define EXP2F(x) __builtin_amdgcn_exp2f(x)
#endif
#endif
#ifndef EXP2F
#define EXP2F(x) __expf((x) * 0.69314718055994531f)
#endif

__device__ __forceinline__ float bf2f(u16 h) {
  return __uint_as_float(((unsigned int)h) << 16);
}
__device__ __forceinline__ u16 f2bf(float f) {  // RNE
  unsigned int u = __float_as_uint(f);
  u += 0x7fffu + ((u >> 16) & 1u);
  return (u16)(u >> 16);
}

__device__ __forceinline__ void gload_lds16(const void* g, void* l) {
  __builtin_amdgcn_global_load_lds(
      (__attribute__((address_space(1))) void*)(g),
      (__attribute__((address_space(3))) void*)(l), 16, 0, 0);
}

// ---------------------------------------------------------------------------
// Dtype detector (flag=1 -> fp32 inputs).
// ---------------------------------------------------------------------------
__global__ __launch_bounds__(256) void detect_dtype(const u16* __restrict__ x,
                                                    int* __restrict__ flag) {
  __shared__ int cnt[256];
  int c = 0;
#pragma unroll
  for (int j = 0; j < 8; ++j) {
    float v = bf2f(x[threadIdx.x * 8 + j]);
    float a = fabsf(v);
    if (a >= 1e-4f && a <= 64.0f) ++c;
  }
  cnt[threadIdx.x] = c;
  __syncthreads();
  if (threadIdx.x == 0) {
    int t = 0;
    for (int i = 0; i < 256; ++i) t += cnt[i];
    flag[0] = (t < 1638) ? 1 : 0;
  }
}

__global__ __launch_bounds__(256) void cvt_copy(const void* __restrict__ in,
                                                u16* __restrict__ out,
                                                const int* __restrict__ flagp,
                                                long n) {
  long idx = ((long)blockIdx.x * 256 + threadIdx.x) * 4;
  if (idx >= n) return;
  if (*flagp) {
    float4 v = *(const float4*)((const float*)in + idx);
    out[idx] = f2bf(v.x); out[idx + 1] = f2bf(v.y);
    out[idx + 2] = f2bf(v.z); out[idx + 3] = f2bf(v.w);
  } else {
    *(u16x4*)(out + idx) = *(const u16x4*)((const u16*)in + idx);
  }
}

__global__ __launch_bounds__(256) void cvt_vecs(
    const void* s0, const void* s1, const void* s2, const void* s3,
    const void* s4, const void* s5, const void* s6, u16* __restrict__ dst,
    const int* __restrict__ flagp) {
  const int lens[7] = {1024, 1024, 1024, 4096, 1024, 1024, 1024};
  const int offs[7] = {0, 1024, 2048, 3072, 7168, 8192, 9216};
  const void* srcs[7] = {s0, s1, s2, s3, s4, s5, s6};
  int w = blockIdx.x;
  int f = *flagp;
  for (int i = threadIdx.x; i < lens[w]; i += 256)
    dst[offs[w] + i] = f ? f2bf(((const float*)srcs[w])[i])
                         : ((const u16*)srcs[w])[i];
}

// ---------------------------------------------------------------------------
// Batched transpose + convert: out[b][c*R+r] = cvt(in[b][r*C+c]).
// ---------------------------------------------------------------------------
__global__ __launch_bounds__(256) void transpose_cvt(
    const void* __restrict__ in, u16* __restrict__ out, int R, int C,
    long inBS, long outBS, const int* __restrict__ flagp) {
  __shared__ u16 tile[32][33];
  int f = *flagp;
  u16* ob = out + (long)blockIdx.z * outBS;
  int c = blockIdx.x * 32 + threadIdx.x;
  int r0 = blockIdx.y * 32;
  if (f) {
    const float* ib = (const float*)in + (long)blockIdx.z * inBS;
#pragma unroll
    for (int i = threadIdx.y; i < 32; i += 8)
      tile[i][threadIdx.x] = f2bf(ib[(long)(r0 + i) * C + c]);
  } else {
    const u16* ib = (const u16*)in + (long)blockIdx.z * inBS;
#pragma unroll
    for (int i = threadIdx.y; i < 32; i += 8)
      tile[i][threadIdx.x] = ib[(long)(r0 + i) * C + c];
  }
  __syncthreads();
  int r = r0 + threadIdx.x;
  int c0 = blockIdx.x * 32;
#pragma unroll
  for (int i = threadIdx.y; i < 32; i += 8)
    ob[(long)(c0 + i) * R + r] = tile[threadIdx.x][i];
}

// ---------------------------------------------------------------------------
// Merged Wq/Wk/Wv transpose: grid (2, 32, 48); z>>4 picks the source,
// z&15 is the head batch.  R=1024, C=64 per head-batch slab of 16 heads.
// ---------------------------------------------------------------------------
__global__ __launch_bounds__(256) void transpose_qkv(
    const void* __restrict__ s0, const void* __restrict__ s1,
    const void* __restrict__ s2, u16* __restrict__ out,
    const int* __restrict__ flagp) {
  __shared__ u16 tile[32][33];
  const int f = *flagp;
  const int z = blockIdx.z;
  const int which = z >> 4, zz = z & 15;
  const void* in = which == 0 ? s0 : (which == 1 ? s1 : s2);
  u16* ob = out + (long)which * 1048576 + (long)zz * 65536;
  const long inOff = (long)zz * 65536;
  const int C = 64, R = 1024;
  int c = blockIdx.x * 32 + threadIdx.x;
  int r0 = blockIdx.y * 32;
  if (f) {
    const float* ib = (const float*)in + inOff;
#pragma unroll
    for (int i = threadIdx.y; i < 32; i += 8)
      tile[i][threadIdx.x] = f2bf(ib[(long)(r0 + i) * C + c]);
  } else {
    const u16* ib = (const u16*)in + inOff;
#pragma unroll
    for (int i = threadIdx.y; i < 32; i += 8)
      tile[i][threadIdx.x] = ib[(long)(r0 + i) * C + c];
  }
  __syncthreads();
  int r = r0 + threadIdx.x;
  int c0 = blockIdx.x * 32;
#pragma unroll
  for (int i = threadIdx.y; i < 32; i += 8)
    ob[(long)(c0 + i) * R + r] = tile[threadIdx.x][i];
}

// ---------------------------------------------------------------------------
// Pre-swizzle K and V into MFMA fragment order.
// ---------------------------------------------------------------------------
__global__ __launch_bounds__(256) void kv_frag(const u16* __restrict__ qkv,
                                               u16* __restrict__ KF,
                                               u16* __restrict__ VF) {
  __shared__ u16 Kt[64][72];
  __shared__ u16 Vt[64][72];
  const int jblk = blockIdx.x, bh = blockIdx.y;
  const int b = bh >> 4, h = bh & 15;
  const int tid = threadIdx.x;
  const long j0 = jblk * 64;

  {
    int tt = tid >> 2, c0 = (tid & 3) * 16;
    const u16* src = qkv + (long)(b * 2048 + j0 + tt) * 3072 + h * 64 + c0;
    *(u16x8*)(&Kt[tt][c0]) = *(const u16x8*)(src + 1024);
    *(u16x8*)(&Kt[tt][c0 + 8]) = *(const u16x8*)(src + 1024 + 8);
    *(u16x8*)(&Vt[tt][c0]) = *(const u16x8*)(src + 2048);
    *(u16x8*)(&Vt[tt][c0 + 8]) = *(const u16x8*)(src + 2048 + 8);
  }
  __syncthreads();

  long obase = ((long)bh * 32 + jblk) * 8 * 512;
#pragma unroll
  for (int si = 0; si < 2; ++si) {
    int s = tid * 2 + si;
    int f = s >> 6, ln = s & 63;
    int kt = f >> 2, nt = f & 3;
    int lr = ln & 15, lq = ln >> 4;
    u16x8 ko, vo;
#pragma unroll
    for (int j = 0; j < 8; ++j) {
      ko[j] = Kt[nt * 16 + lr][kt * 32 + lq * 8 + j];
      vo[j] = Vt[kt * 32 + lq * 8 + j][nt * 16 + lr];
    }
    *(u16x8*)(KF + obase + (long)s * 8) = ko;
    *(u16x8*)(VF + obase + (long)s * 8) = vo;
  }
}

// ---------------------------------------------------------------------------
// gemm2ph: C[M,N] = A[M,K] @ Bt[N,K]^T (+ epilogue).  256xBN tile, BK=64,
// 2-phase double-buffered, one barrier per K-tile.  512 threads (8 waves).
// LDS(row,slot) holds global chunk slot^(row&7); read undoes (0 conflicts,
// verified r2/r4/r8/r9).  EPI 0: bf16.  EPI 2: +bias,gelu.  EPI 3: +bias.
// ---------------------------------------------------------------------------
__device__ __forceinline__ bf16x8 fragld64(const u16* lb, int row, int ks,
                                           int lq) {
  int slot = ((ks << 2) | lq) ^ (row & 7);
  return *(const bf16x8*)(lb + row * 64 + slot * 8);
}

template <int EPI, int BN>
__global__ __launch_bounds__(512, 2) void gemm2ph(
    const u16* __restrict__ A, const u16* __restrict__ Bt,
    const u16* __restrict__ bias, u16* __restrict__ Cout,
    int M, int N, int K) {
  static_assert(BN == 256 || BN == 128, "");
  constexpr int NFQ = BN / 128;  // B fragments per quadrant
  __shared__ u16 As[2][16384];
  __shared__ u16 Bs[2][BN * 64];
  const int tid = threadIdx.x;
  const int wave = tid >> 6, lane = tid & 63;
  const int lr = lane & 15, lq = lane >> 4;

  const int MT = M >> 8, NTt = N / BN;
  const int nwg = MT * NTt;
  int wg = blockIdx.x;
  if (!(nwg & 7)) wg = (wg & 7) * (nwg >> 3) + (wg >> 3);  // XCD swizzle
  const int tm = wg % MT, tn = wg / MT;
  const long m0 = (long)tm << 8;
  const long n0 = (long)tn * BN;

  const int wm = (wave >> 2) << 7;       // 0 / 128
  const int wn = (wave & 3) * (BN / 4);  // per-wave N offset

  const int srow = lane >> 3;
  const int skoff = ((lane & 7) ^ srow) * 8;  // pre-swizzled global source

  auto stage = [&](int buf, int t) {
#pragma unroll
    for (int j = 0; j < 4; ++j)
      gload_lds16(
          A + (m0 + j * 64 + wave * 8 + srow) * (long)K + t * 64 + skoff,
          &As[buf][j * 4096 + (wave << 9)]);
#pragma unroll
    for (int j = 0; j < BN / 64; ++j)
      gload_lds16(
          Bt + (n0 + j * 64 + wave * 8 + srow) * (long)K + t * 64 + skoff,
          &Bs[buf][j * 4096 + (wave << 9)]);
  };

  f32x4 acc[8][2 * NFQ] = {};
  const int NT = K >> 6;
  int cur = 0;

  stage(0, 0);
  __syncthreads();

  for (int t = 0; t < NT; ++t) {
    const u16* Ab = As[cur];
    const u16* Bb = Bs[cur];
    if (t + 1 < NT) stage(cur ^ 1, t + 1);  // prefetch overlaps compute

    bf16x8 a_[4][2], b0_[NFQ][2], b1_[NFQ][2];
    // quadrant (m-lo, n-lo)
#pragma unroll
    for (int mf = 0; mf < 4; ++mf)
#pragma unroll
      for (int ks = 0; ks < 2; ++ks)
        a_[mf][ks] = fragld64(Ab, wm + mf * 16 + lr, ks, lq);
#pragma unroll
    for (int nf = 0; nf < NFQ; ++nf)
#pragma unroll
      for (int ks = 0; ks < 2; ++ks)
        b0_[nf][ks] = fragld64(Bb, wn + nf * 16 + lr, ks, lq);
#pragma unroll
    for (int mf = 0; mf < 4; ++mf)
#pragma unroll
      for (int nf = 0; nf < NFQ; ++nf)
#pragma unroll
        for (int ks = 0; ks < 2; ++ks)
          acc[mf][nf] = __builtin_amdgcn_mfma_f32_16x16x32_bf16(
              a_[mf][ks], b0_[nf][ks], acc[mf][nf], 0, 0, 0);
    // quadrant (m-lo, n-hi)
#pragma unroll
    for (int nf = 0; nf < NFQ; ++nf)
#pragma unroll
      for (int ks = 0; ks < 2; ++ks)
        b1_[nf][ks] = fragld64(Bb, wn + BN / 8 + nf * 16 + lr, ks, lq);
#pragma unroll
    for (int mf = 0; mf < 4; ++mf)
#pragma unroll
      for (int nf = 0; nf < NFQ; ++nf)
#pragma unroll
        for (int ks = 0; ks < 2; ++ks)
          acc[mf][NFQ + nf] = __builtin_amdgcn_mfma_f32_16x16x32_bf16(
              a_[mf][ks], b1_[nf][ks], acc[mf][NFQ + nf], 0, 0, 0);
    // quadrant (m-hi, n-hi)
#pragma unroll
    for (int mf = 0; mf < 4; ++mf)
#pragma unroll
      for (int ks = 0; ks < 2; ++ks)
        a_[mf][ks] = fragld64(Ab, wm + 64 + mf * 16 + lr, ks, lq);
#pragma unroll
    for (int mf = 0; mf < 4; ++mf)
#pragma unroll
      for (int nf = 0; nf < NFQ; ++nf)
#pragma unroll
        for (int ks = 0; ks < 2; ++ks)
          acc[4 + mf][NFQ + nf] = __builtin_amdgcn_mfma_f32_16x16x32_bf16(
              a_[mf][ks], b1_[nf][ks], acc[4 + mf][NFQ + nf], 0, 0, 0);
    // quadrant (m-hi, n-lo)
#pragma unroll
    for (int mf = 0; mf < 4; ++mf)
#pragma unroll
      for (int nf = 0; nf < NFQ; ++nf)
#pragma unroll
        for (int ks = 0; ks < 2; ++ks)
          acc[4 + mf][nf] = __builtin_amdgcn_mfma_f32_16x16x32_bf16(
              a_[mf][ks], b0_[nf][ks], acc[4 + mf][nf], 0, 0, 0);

    __syncthreads();
    cur ^= 1;
  }

  const int rq = lq * 4;
#pragma unroll
  for (int mf = 0; mf < 8; ++mf)
#pragma unroll
    for (int nf2 = 0; nf2 < 2 * NFQ; ++nf2) {
      const int col = (int)n0 + wn + nf2 * 16 + lr;
#pragma unroll
      for (int r = 0; r < 4; ++r) {
        const long row = m0 + wm + mf * 16 + rq + r;
        float v = acc[mf][nf2][r];
        if (EPI == 2) {
          v += bf2f(bias[col]);
          v = 0.5f * v * (1.0f + erff(v * 0.70710678118654752f));
        } else if (EPI == 3) {
          v += bf2f(bias[col]);
        }
        Cout[row * (long)N + col] = f2bf(v);
      }
    }
}

// ---------------------------------------------------------------------------
// Flash attention v9.  Grid (T/128, B*H), block 256, (256,3): 3 blocks/CU.
// Each wave: 32 Q-rows.  S^T = K.Q^T via mfma(bk, aq) -> per-lane softmax.
// Ps: 32 rows x 64 u16, 16B-window XOR swizzle (wphys = wlog ^ (lr&7)).
// ---------------------------------------------------------------------------
__global__ __launch_bounds__(256, 3) void flash_attn(
    const u16* __restrict__ qkv, const u16* __restrict__ KF,
    const u16* __restrict__ VF, u16* __restrict__ cat) {
  const int T = 2048, LD = 3072;
  const float QSCALE = 0.18033688011112042f;  // log2e / 8
  const float EXPC = 4.3280851226677321f;     // 3 * log2e (static max)
  const int bh = blockIdx.y;
  const int b = bh >> 4, h = bh & 15;
  const int tid = threadIdx.x, wave = tid >> 6, lane = tid & 63;
  const int lr = lane & 15, lq = lane >> 4;

  __shared__ u16 Ps[4 * 32 * 64];  // per-wave 32 rows x 64 u16, swizzled
  u16* Pw = Ps + wave * 32 * 64;

  const u16* Qb = qkv + (long)(b * 2048) * LD + h * 64;
  const long fbase = (long)bh * 32 * 8 * 512;

  bf16x8 aq[2][2];
#pragma unroll
  for (int st = 0; st < 2; ++st) {
    int qrow = blockIdx.x * 128 + wave * 32 + st * 16 + lr;
#pragma unroll
    for (int kt = 0; kt < 2; ++kt) {
      u16x8 q = *(const u16x8*)(Qb + (long)qrow * LD + kt * 32 + lq * 8);
      bf16x8 t;
#pragma unroll
      for (int j = 0; j < 8; ++j) t[j] = (__bf16)(bf2f(q[j]) * QSCALE);
      aq[st][kt] = t;
    }
  }

  f32x4 o[2][4] = {};
  float lsum[2] = {0.0f, 0.0f};

  for (int jblk = 0; jblk < T / 64; ++jblk) {
    const u16* kf = KF + fbase + (long)jblk * 8 * 512;
    const u16* vf = VF + fbase + (long)jblk * 8 * 512;

    bf16x8 bk[2][4];
#pragma unroll
    for (int kt = 0; kt < 2; ++kt)
#pragma unroll
      for (int nt = 0; nt < 4; ++nt)
        bk[kt][nt] = *(const bf16x8*)(kf + (kt * 4 + nt) * 512 + lane * 8);

    f32x4 s[2][4] = {};
    __builtin_amdgcn_s_setprio(1);
#pragma unroll
    for (int st = 0; st < 2; ++st)
#pragma unroll
      for (int nt = 0; nt < 4; ++nt)
#pragma unroll
        for (int kt = 0; kt < 2; ++kt)
          s[st][nt] = __builtin_amdgcn_mfma_f32_16x16x32_bf16(
              bk[kt][nt], aq[st][kt], s[st][nt], 0, 0, 0);
    __builtin_amdgcn_s_setprio(0);

    bf16x8 bv[2][4];
#pragma unroll
    for (int kt = 0; kt < 2; ++kt)
#pragma unroll
      for (int nt = 0; nt < 4; ++nt)
        bv[kt][nt] = *(const bf16x8*)(vf + (kt * 4 + nt) * 512 + lane * 8);

#pragma unroll
    for (int st = 0; st < 2; ++st)
#pragma unroll
      for (int nt = 0; nt < 4; ++nt) {
        f32x4 p;
#pragma unroll
        for (int r = 0; r < 4; ++r) p[r] = EXP2F(s[st][nt][r] - EXPC);
        lsum[st] += (p[0] + p[1]) + (p[2] + p[3]);
        bf16x4 pk;
#pragma unroll
        for (int r = 0; r < 4; ++r) pk[r] = (__bf16)p[r];
        int wph = (nt * 2 + (lq >> 1)) ^ (lr & 7);
        *(bf16x4*)(Pw + (st * 16 + lr) * 64 + wph * 8 + (lq & 1) * 4) = pk;
      }

#pragma unroll
    for (int st = 0; st < 2; ++st)
#pragma unroll
      for (int kt = 0; kt < 2; ++kt) {
        bf16x8 ap = *(const bf16x8*)(
            Pw + (st * 16 + lr) * 64 + (((kt * 4 + lq) ^ (lr & 7)) * 8));
        __builtin_amdgcn_s_setprio(1);
#pragma unroll
        for (int nt = 0; nt < 4; ++nt)
          o[st][nt] = __builtin_amdgcn_mfma_f32_16x16x32_bf16(
              ap, bv[kt][nt], o[st][nt], 0, 0, 0);
        __builtin_amdgcn_s_setprio(0);
      }
  }

#pragma unroll
  for (int st = 0; st < 2; ++st) {
    lsum[st] += __shfl_xor(lsum[st], 16, 64);
    lsum[st] += __shfl_xor(lsum[st], 32, 64);
  }

  u16* ob = cat + (long)(b * 2048) * 1024 + h * 64;
#pragma unroll
  for (int st = 0; st < 2; ++st) {
    int trow = blockIdx.x * 128 + wave * 32 + st * 16 + lq * 4;
#pragma unroll
    for (int r = 0; r < 4; ++r) {
      float linv = 1.0f / __shfl(lsum[st], lq * 4 + r, 64);
#pragma unroll
      for (int nt = 0; nt < 4; ++nt)
        ob[(long)(trow + r) * 1024 + nt * 16 + lr] = f2bf(o[st][nt][r] * linv);
    }
  }
}

// ---------------------------------------------------------------------------
// out[row] = res[row] + LN(y[row]) * g + b.   y is bf16.
// ---------------------------------------------------------------------------
__global__ __launch_bounds__(256) void ln_residual(
    const u16* __restrict__ y, const void* __restrict__ res, int res_raw,
    const u16* __restrict__ g, const u16* __restrict__ bb,
    void* __restrict__ out, const int* __restrict__ flagp, int final_out) {
  const long row = blockIdx.x;
  const int tid = threadIdx.x, wave = tid >> 6, lane = tid & 63;
  u16x4 yv = *(const u16x4*)(y + row * 1024 + tid * 4);
  float yy[4];
#pragma unroll
  for (int j = 0; j < 4; ++j) yy[j] = bf2f(yv[j]);
  float s1 = yy[0] + yy[1] + yy[2] + yy[3];
  float s2 = yy[0] * yy[0] + yy[1] * yy[1] + yy[2] * yy[2] + yy[3] * yy[3];
#pragma unroll
  for (int off = 1; off < 64; off <<= 1) {
    s1 += __shfl_xor(s1, off, 64);
    s2 += __shfl_xor(s2, off, 64);
  }
  __shared__ float ws1[4], ws2[4];
  if (lane == 0) { ws1[wave] = s1; ws2[wave] = s2; }
  __syncthreads();
  float t1 = ws1[0] + ws1[1] + ws1[2] + ws1[3];
  float t2 = ws2[0] + ws2[1] + ws2[2] + ws2[3];
  float mu = t1 * (1.0f / 1024.0f);
  float var = t2 * (1.0f / 1024.0f) - mu * mu;
  float rstd = rsqrtf(var + 1e-5f);
  int i = tid * 4;
  bool f32in = res_raw && (*flagp);
  bool f32out = final_out && (*flagp);
#pragma unroll
  for (int j = 0; j < 4; ++j) {
    float rv = f32in ? ((const float*)res)[row * 1024 + i + j]
                     : bf2f(((const u16*)res)[row * 1024 + i + j]);
    float o = rv + (yy[j] - mu) * rstd * bf2f(g[i + j]) + bf2f(bb[i + j]);
    if (f32out)
      ((float*)out)[row * 1024 + i + j] = o;
    else
      ((u16*)out)[row * 1024 + i + j] = f2bf(o);
  }
}

// ---------------------------------------------------------------------------
extern "C" void kernel_launch(void* const* d_in, const int* in_sizes, int n_in,
                              void* d_out, int out_size, void* d_ws,
                              size_t ws_size, hipStream_t stream) {
  const void* x_raw = d_in[0];
  const void* Wq = d_in[1];
  const void* Wk = d_in[2];
  const void* Wv = d_in[3];
  const void* Wo = d_in[4];
  const void* bo = d_in[5];
  const void* ln1g = d_in[6];
  const void* ln1b = d_in[7];
  const void* W1 = d_in[8];
  const void* b1 = d_in[9];
  const void* W2 = d_in[10];
  const void* b2 = d_in[11];
  const void* ln2g = d_in[12];
  const void* ln2b = d_in[13];

  char* ws = (char*)d_ws;
  u16* qkv = (u16*)(ws + 0);              // [8192,3072]
  u16* mha = (u16*)(ws + 0);              // [8192,1024] bf16
  u16* h1 = (u16*)(ws + 0);               // [8192,4096] bf16
  u16* cat = (u16*)(ws + 50331648);       // [8192,1024]
  u16* KF = (u16*)(ws + 67108864);        // frag-order K (16M)
  u16* ff = (u16*)(ws + 67108864);        // [8192,1024] bf16
  u16* xb = (u16*)(ws + 83886080);        // bf16 x
  u16* VF = (u16*)(ws + 83886080);        // frag-order V (16M)
  u16* x1 = (u16*)(ws + 83886080);        // [8192,1024] after flash
  u16* wqkvt = (u16*)(ws + 100663296);    // [3072,1024]
  u16* wot = (u16*)(ws + 106954752);      // [1024,1024]
  u16* w1t = (u16*)(ws + 109051904);      // [4096,1024]
  u16* w2t = (u16*)(ws + 117440512);      // [1024,4096]
  u16* vecs = (u16*)(ws + 125829120);     // packed bias/gain vectors
  int* flag = (int*)(ws + 125853696);     // dtype flag (1 = fp32)

  const u16* v_bo = vecs + 0;
  const u16* v_l1g = vecs + 1024;
  const u16* v_l1b = vecs + 2048;
  const u16* v_b1 = vecs + 3072;
  const u16* v_b2 = vecs + 7168;
  const u16* v_l2g = vecs + 8192;
  const u16* v_l2b = vecs + 9216;

  detect_dtype<<<1, 256, 0, stream>>>((const u16*)x_raw, flag);
  cvt_copy<<<8192, 256, 0, stream>>>(x_raw, xb, flag, 8388608L);
  cvt_vecs<<<7, 256, 0, stream>>>(bo, ln1g, ln1b, b1, b2, ln2g, ln2b, vecs, flag);

  dim3 tb(32, 8);
  // Wq/Wk/Wv merged into one z=48 launch
  transpose_qkv<<<dim3(2, 32, 48), tb, 0, stream>>>(Wq, Wk, Wv, wqkvt, flag);
  transpose_cvt<<<dim3(32, 32, 1), tb, 0, stream>>>(Wo, wot, 1024, 1024, 0, 0, flag);
  transpose_cvt<<<dim3(128, 32, 1), tb, 0, stream>>>(W1, w1t, 1024, 4096, 0, 0, flag);
  transpose_cvt<<<dim3(32, 128, 1), tb, 0, stream>>>(W2, w2t, 4096, 1024, 0, 0, flag);

  // qkv = xb @ Wqkv   (gemm2ph BK=64, BN=128; 768 wgs = 3 even rounds)
  gemm2ph<0, 128><<<768, 512, 0, stream>>>(xb, wqkvt, nullptr, qkv, 8192, 3072, 1024);
  // K/V -> MFMA fragment order
  kv_frag<<<dim3(32, 64), 256, 0, stream>>>(qkv, KF, VF);
  // cat = attention
  flash_attn<<<dim3(16, 64), 256, 0, stream>>>(qkv, KF, VF, cat);
  // mha = cat @ Wo + bo (gemm2ph BN=128; grid 256, measured-best)
  gemm2ph<3, 128><<<256, 512, 0, stream>>>(cat, wot, v_bo, mha, 8192, 1024, 1024);
  // x1 = x_raw + LN(mha)
  ln_residual<<<8192, 256, 0, stream>>>(mha, x_raw, 1, v_l1g, v_l1b, x1, flag, 0);
  // h1 = gelu(x1 @ W1 + b1) (gemm2ph BN=256; 512 wgs, measured-best)
  gemm2ph<2, 256><<<512, 512, 0, stream>>>(x1, w1t, v_b1, h1, 8192, 4096, 1024);
  // ff = h1 @ W2 + b2 (gemm2ph BN=128; grid 256, measured-best)
  gemm2ph<3, 128><<<256, 512, 0, stream>>>(h1, w2t, v_b2, ff, 8192, 1024, 4096);
  // out = x1 + LN(ff)
  ln_residual<<<8192, 256, 0, stream>>>(ff, x1, 0, v_l2g, v_l2b, d_out, flag, 1);
}

// Round 12
// 614.292 us; speedup vs baseline: 1.0161x; 1.0057x over previous
//
#include <hip/hip_runtime.h>
#include <math.h>

// ---------------------------------------------------------------------------
// Encoder block on MI355X (gfx950).  B=4, T=2048, E=1024, H=16, Dh=64, FF=4096.
// Inputs may be bf16 or fp32 (harness-dependent, detector-classified).
// GEMM v9 (r11 best = 617.8us) + plumbing round:
//  - kv_frag FUSED into the QKV gemm epilogue (gemm_qkv): K/V output cols are
//    written directly in MFMA fragment order (index maps derived from and
//    verified against kv_frag).  Saves the 64MB-traffic kv_frag kernel.
//    Workspace remapped: VF->48M (old cat), cat->80M (old xb, dead post-QKV),
//    x1 stays 80M (cat dead post-Wo).  Liveness chain re-verified.
//  - ALL setup kernels merged into one setup_all launch (cvt_copy, cvt_vecs,
//    4 transposes; block-range dispatch).  15 -> 9 launches total.
// GEMM core unchanged: gemm2ph 256xBN BK=64 2-phase dbuf (structural ceiling
// ~590 TF = 90% of m248's 2-phase limit; 8-phase escape failed 2x).
// Attention v9: transposed flash, (256,3), setprio, swizzled Ps.
// ---------------------------------------------------------------------------

using u16 = unsigned short;
typedef __bf16 bf16x8 __attribute__((ext_vector_type(8)));
typedef __bf16 bf16x4 __attribute__((ext_vector_type(4)));
typedef unsigned short u16x8 __attribute__((ext_vector_type(8)));
typedef unsigned short u16x4 __attribute__((ext_vector_type(4)));
typedef float f32x4 __attribute__((ext_vector_type(4)));

#if defined(__has_builtin)
#if __has_builtin(__builtin_amdgcn_exp2f)
#define EXP2F(x) __builtin_amdgcn_exp2f(x)
#endif
#endif
#ifndef EXP2F
#define EXP2F(x) __expf((x) * 0.69314718055994531f)
#endif

__device__ __forceinline__ float bf2f(u16 h) {
  return __uint_as_float(((unsigned int)h) << 16);
}
__device__ __forceinline__ u16 f2bf(float f) {  // RNE
  unsigned int u = __float_as_uint(f);
  u += 0x7fffu + ((u >> 16) & 1u);
  return (u16)(u >> 16);
}

__device__ __forceinline__ void gload_lds16(const void* g, void* l) {
  __builtin_amdgcn_global_load_lds(
      (__attribute__((address_space(1))) void*)(g),
      (__attribute__((address_space(3))) void*)(l), 16, 0, 0);
}

// ---------------------------------------------------------------------------
// Dtype detector (flag=1 -> fp32 inputs).
// ---------------------------------------------------------------------------
__global__ __launch_bounds__(256) void detect_dtype(const u16* __restrict__ x,
                                                    int* __restrict__ flag) {
  __shared__ int cnt[256];
  int c = 0;
#pragma unroll
  for (int j = 0; j < 8; ++j) {
    float v = bf2f(x[threadIdx.x * 8 + j]);
    float a = fabsf(v);
    if (a >= 1e-4f && a <= 64.0f) ++c;
  }
  cnt[threadIdx.x] = c;
  __syncthreads();
  if (threadIdx.x == 0) {
    int t = 0;
    for (int i = 0; i < 256; ++i) t += cnt[i];
    flag[0] = (t < 1638) ? 1 : 0;
  }
}

// ---------------------------------------------------------------------------
// setup_all: one launch for every flag-dependent setup task.
// Blocks: [0,8192)   cvt_copy x -> xb (bf16)
//         [8192,8199) cvt_vecs (bias/gain vectors)
//         [8199,11271) Wq/Wk/Wv transpose (3072 blocks: z=q/64, rem: bx=q&1,
//                      by=(q>>1)&31; z>>4 selects src, z&15 is head slab)
//         [11271,12295) Wo transpose (bx=q&31, by=q>>5)
//         [12295,16391) W1 transpose (bx=q&127, by=q>>7)
//         [16391,20487) W2 transpose (bx=q&31, by=q>>5)
// ---------------------------------------------------------------------------
__global__ __launch_bounds__(256) void setup_all(
    const void* __restrict__ x_raw, u16* __restrict__ xb,
    const void* s0, const void* s1, const void* s2, const void* s3,
    const void* s4, const void* s5, const void* s6, u16* __restrict__ vecs,
    const void* Wq, const void* Wk, const void* Wv, u16* __restrict__ wqkvt,
    const void* Wo, u16* __restrict__ wot,
    const void* W1, u16* __restrict__ w1t,
    const void* W2, u16* __restrict__ w2t, const int* __restrict__ flagp) {
  const int f = *flagp;
  const int id = blockIdx.x;
  const int tid = threadIdx.x;

  if (id < 8192) {  // cvt_copy
    long idx = ((long)id * 256 + tid) * 4;
    if (f) {
      float4 v = *(const float4*)((const float*)x_raw + idx);
      xb[idx] = f2bf(v.x); xb[idx + 1] = f2bf(v.y);
      xb[idx + 2] = f2bf(v.z); xb[idx + 3] = f2bf(v.w);
    } else {
      *(u16x4*)(xb + idx) = *(const u16x4*)((const u16*)x_raw + idx);
    }
    return;
  }
  if (id < 8199) {  // cvt_vecs
    const int lens[7] = {1024, 1024, 1024, 4096, 1024, 1024, 1024};
    const int offs[7] = {0, 1024, 2048, 3072, 7168, 8192, 9216};
    const void* srcs[7] = {s0, s1, s2, s3, s4, s5, s6};
    int w = id - 8192;
    for (int i = tid; i < lens[w]; i += 256)
      vecs[offs[w] + i] = f ? f2bf(((const float*)srcs[w])[i])
                            : ((const u16*)srcs[w])[i];
    return;
  }

  // transpose segments
  __shared__ u16 tile[32][33];
  const void* in;
  u16* out;
  int R, C, bx, by;
  if (id < 11271) {  // Wq/Wk/Wv
    int q = id - 8199;
    int bz = q >> 6, rem = q & 63;
    bx = rem & 1; by = rem >> 1;
    int which = bz >> 4, zz = bz & 15;
    const void* src = which == 0 ? Wq : (which == 1 ? Wk : Wv);
    in = (const char*)src + (long)zz * 65536 * (f ? 4 : 2);
    out = wqkvt + (long)which * 1048576 + (long)zz * 65536;
    R = 1024; C = 64;
  } else if (id < 12295) {  // Wo
    int q = id - 11271; bx = q & 31; by = q >> 5;
    in = Wo; out = wot; R = 1024; C = 1024;
  } else if (id < 16391) {  // W1
    int q = id - 12295; bx = q & 127; by = q >> 7;
    in = W1; out = w1t; R = 1024; C = 4096;
  } else {  // W2
    int q = id - 16391; bx = q & 31; by = q >> 5;
    in = W2; out = w2t; R = 4096; C = 1024;
  }
  const int tx = tid & 31, ty = tid >> 5;
  int c = bx * 32 + tx, r0 = by * 32;
  if (f) {
    const float* ib = (const float*)in;
#pragma unroll
    for (int i = ty; i < 32; i += 8)
      tile[i][tx] = f2bf(ib[(long)(r0 + i) * C + c]);
  } else {
    const u16* ib = (const u16*)in;
#pragma unroll
    for (int i = ty; i < 32; i += 8)
      tile[i][tx] = ib[(long)(r0 + i) * C + c];
  }
  __syncthreads();
  int r = r0 + tx, c0 = bx * 32;
#pragma unroll
  for (int i = ty; i < 32; i += 8)
    out[(long)(c0 + i) * R + r] = tile[tx][i];
}

// ---------------------------------------------------------------------------
// Shared fragment read: LDS(row,slot) holds global chunk slot^(row&7);
// read undoes the XOR (0 conflicts, verified r2/r4/r8/r9).
// ---------------------------------------------------------------------------
__device__ __forceinline__ bf16x8 fragld64(const u16* lb, int row, int ks,
                                           int lq) {
  int slot = ((ks << 2) | lq) ^ (row & 7);
  return *(const bf16x8*)(lb + row * 64 + slot * 8);
}

// ---------------------------------------------------------------------------
// gemm2ph: C[M,N] = A[M,K] @ Bt[N,K]^T (+ epilogue).  256xBN tile, BK=64,
// 2-phase double-buffered, one barrier per K-tile.  512 threads (8 waves).
// EPI 2: +bias,gelu.  EPI 3: +bias.
// ---------------------------------------------------------------------------
template <int EPI, int BN>
__global__ __launch_bounds__(512, 2) void gemm2ph(
    const u16* __restrict__ A, const u16* __restrict__ Bt,
    const u16* __restrict__ bias, u16* __restrict__ Cout,
    int M, int N, int K) {
  static_assert(BN == 256 || BN == 128, "");
  constexpr int NFQ = BN / 128;  // B fragments per quadrant
  __shared__ u16 As[2][16384];
  __shared__ u16 Bs[2][BN * 64];
  const int tid = threadIdx.x;
  const int wave = tid >> 6, lane = tid & 63;
  const int lr = lane & 15, lq = lane >> 4;

  const int MT = M >> 8, NTt = N / BN;
  const int nwg = MT * NTt;
  int wg = blockIdx.x;
  if (!(nwg & 7)) wg = (wg & 7) * (nwg >> 3) + (wg >> 3);  // XCD swizzle
  const int tm = wg % MT, tn = wg / MT;
  const long m0 = (long)tm << 8;
  const long n0 = (long)tn * BN;

  const int wm = (wave >> 2) << 7;       // 0 / 128
  const int wn = (wave & 3) * (BN / 4);  // per-wave N offset

  const int srow = lane >> 3;
  const int skoff = ((lane & 7) ^ srow) * 8;  // pre-swizzled global source

  auto stage = [&](int buf, int t) {
#pragma unroll
    for (int j = 0; j < 4; ++j)
      gload_lds16(
          A + (m0 + j * 64 + wave * 8 + srow) * (long)K + t * 64 + skoff,
          &As[buf][j * 4096 + (wave << 9)]);
#pragma unroll
    for (int j = 0; j < BN / 64; ++j)
      gload_lds16(
          Bt + (n0 + j * 64 + wave * 8 + srow) * (long)K + t * 64 + skoff,
          &Bs[buf][j * 4096 + (wave << 9)]);
  };

  f32x4 acc[8][2 * NFQ] = {};
  const int NT = K >> 6;
  int cur = 0;

  stage(0, 0);
  __syncthreads();

  for (int t = 0; t < NT; ++t) {
    const u16* Ab = As[cur];
    const u16* Bb = Bs[cur];
    if (t + 1 < NT) stage(cur ^ 1, t + 1);  // prefetch overlaps compute

    bf16x8 a_[4][2], b0_[NFQ][2], b1_[NFQ][2];
#pragma unroll
    for (int mf = 0; mf < 4; ++mf)
#pragma unroll
      for (int ks = 0; ks < 2; ++ks)
        a_[mf][ks] = fragld64(Ab, wm + mf * 16 + lr, ks, lq);
#pragma unroll
    for (int nf = 0; nf < NFQ; ++nf)
#pragma unroll
      for (int ks = 0; ks < 2; ++ks)
        b0_[nf][ks] = fragld64(Bb, wn + nf * 16 + lr, ks, lq);
#pragma unroll
    for (int mf = 0; mf < 4; ++mf)
#pragma unroll
      for (int nf = 0; nf < NFQ; ++nf)
#pragma unroll
        for (int ks = 0; ks < 2; ++ks)
          acc[mf][nf] = __builtin_amdgcn_mfma_f32_16x16x32_bf16(
              a_[mf][ks], b0_[nf][ks], acc[mf][nf], 0, 0, 0);
#pragma unroll
    for (int nf = 0; nf < NFQ; ++nf)
#pragma unroll
      for (int ks = 0; ks < 2; ++ks)
        b1_[nf][ks] = fragld64(Bb, wn + BN / 8 + nf * 16 + lr, ks, lq);
#pragma unroll
    for (int mf = 0; mf < 4; ++mf)
#pragma unroll
      for (int nf = 0; nf < NFQ; ++nf)
#pragma unroll
        for (int ks = 0; ks < 2; ++ks)
          acc[mf][NFQ + nf] = __builtin_amdgcn_mfma_f32_16x16x32_bf16(
              a_[mf][ks], b1_[nf][ks], acc[mf][NFQ + nf], 0, 0, 0);
#pragma unroll
    for (int mf = 0; mf < 4; ++mf)
#pragma unroll
      for (int ks = 0; ks < 2; ++ks)
        a_[mf][ks] = fragld64(Ab, wm + 64 + mf * 16 + lr, ks, lq);
#pragma unroll
    for (int mf = 0; mf < 4; ++mf)
#pragma unroll
      for (int nf = 0; nf < NFQ; ++nf)
#pragma unroll
        for (int ks = 0; ks < 2; ++ks)
          acc[4 + mf][NFQ + nf] = __builtin_amdgcn_mfma_f32_16x16x32_bf16(
              a_[mf][ks], b1_[nf][ks], acc[4 + mf][NFQ + nf], 0, 0, 0);
#pragma unroll
    for (int mf = 0; mf < 4; ++mf)
#pragma unroll
      for (int nf = 0; nf < NFQ; ++nf)
#pragma unroll
        for (int ks = 0; ks < 2; ++ks)
          acc[4 + mf][nf] = __builtin_amdgcn_mfma_f32_16x16x32_bf16(
              a_[mf][ks], b0_[nf][ks], acc[4 + mf][nf], 0, 0, 0);

    __syncthreads();
    cur ^= 1;
  }

  const int rq = lq * 4;
#pragma unroll
  for (int mf = 0; mf < 8; ++mf)
#pragma unroll
    for (int nf2 = 0; nf2 < 2 * NFQ; ++nf2) {
      const int col = (int)n0 + wn + nf2 * 16 + lr;
#pragma unroll
      for (int r = 0; r < 4; ++r) {
        const long row = m0 + wm + mf * 16 + rq + r;
        float v = acc[mf][nf2][r];
        if (EPI == 2) {
          v += bf2f(bias[col]);
          v = 0.5f * v * (1.0f + erff(v * 0.70710678118654752f));
        } else if (EPI == 3) {
          v += bf2f(bias[col]);
        }
        Cout[row * (long)N + col] = f2bf(v);
      }
    }
}

// ---------------------------------------------------------------------------
// gemm_qkv: same core as gemm2ph<*,128> (M=8192, N=3072, K=1024), but the
// epilogue writes Q to qkv rows and K/V DIRECTLY in MFMA fragment order
// (kv_frag fused).  Index maps verified against kv_frag:
//   K: KF[((b*16+h)*32 + t/64)*4096 + ((d>>5)*4 + ((t>>4)&3))*512
//         + (((d>>3)&3)*16 + (t&15))*8 + (d&7)] = K[t][d]
//   V: VF[((b*16+h)*32 + t/64)*4096 + (((t>>5)&1)*4 + (d>>4))*512
//         + (((t>>3)&3)*16 + (d&15))*8 + (t&7)] = V[t][d]
// Region (Q/K/V) is block-uniform: n0 bands at 1024/2048 are BN-multiples.
// ---------------------------------------------------------------------------
__global__ __launch_bounds__(512, 2) void gemm_qkv(
    const u16* __restrict__ A, const u16* __restrict__ Bt,
    u16* __restrict__ Qout, u16* __restrict__ KF, u16* __restrict__ VF) {
  const int M = 8192, N = 3072, K = 1024;
  constexpr int BN = 128;
  __shared__ u16 As[2][16384];
  __shared__ u16 Bs[2][BN * 64];
  const int tid = threadIdx.x;
  const int wave = tid >> 6, lane = tid & 63;
  const int lr = lane & 15, lq = lane >> 4;

  const int MT = M >> 8, NTt = N / BN;
  const int nwg = MT * NTt;
  int wg = blockIdx.x;
  if (!(nwg & 7)) wg = (wg & 7) * (nwg >> 3) + (wg >> 3);  // XCD swizzle
  const int tm = wg % MT, tn = wg / MT;
  const long m0 = (long)tm << 8;
  const long n0 = (long)tn * BN;

  const int wm = (wave >> 2) << 7;
  const int wn = (wave & 3) * (BN / 4);

  const int srow = lane >> 3;
  const int skoff = ((lane & 7) ^ srow) * 8;

  auto stage = [&](int buf, int t) {
#pragma unroll
    for (int j = 0; j < 4; ++j)
      gload_lds16(
          A + (m0 + j * 64 + wave * 8 + srow) * (long)K + t * 64 + skoff,
          &As[buf][j * 4096 + (wave << 9)]);
#pragma unroll
    for (int j = 0; j < BN / 64; ++j)
      gload_lds16(
          Bt + (n0 + j * 64 + wave * 8 + srow) * (long)K + t * 64 + skoff,
          &Bs[buf][j * 4096 + (wave << 9)]);
  };

  f32x4 acc[8][2] = {};
  const int NT = K >> 6;
  int cur = 0;

  stage(0, 0);
  __syncthreads();

  for (int t = 0; t < NT; ++t) {
    const u16* Ab = As[cur];
    const u16* Bb = Bs[cur];
    if (t + 1 < NT) stage(cur ^ 1, t + 1);

    bf16x8 a_[4][2], b0_[2], b1_[2];
#pragma unroll
    for (int mf = 0; mf < 4; ++mf)
#pragma unroll
      for (int ks = 0; ks < 2; ++ks)
        a_[mf][ks] = fragld64(Ab, wm + mf * 16 + lr, ks, lq);
#pragma unroll
    for (int ks = 0; ks < 2; ++ks) b0_[ks] = fragld64(Bb, wn + lr, ks, lq);
#pragma unroll
    for (int mf = 0; mf < 4; ++mf)
#pragma unroll
      for (int ks = 0; ks < 2; ++ks)
        acc[mf][0] = __builtin_amdgcn_mfma_f32_16x16x32_bf16(
            a_[mf][ks], b0_[ks], acc[mf][0], 0, 0, 0);
#pragma unroll
    for (int ks = 0; ks < 2; ++ks)
      b1_[ks] = fragld64(Bb, wn + 16 + lr, ks, lq);
#pragma unroll
    for (int mf = 0; mf < 4; ++mf)
#pragma unroll
      for (int ks = 0; ks < 2; ++ks)
        acc[mf][1] = __builtin_amdgcn_mfma_f32_16x16x32_bf16(
            a_[mf][ks], b1_[ks], acc[mf][1], 0, 0, 0);
#pragma unroll
    for (int mf = 0; mf < 4; ++mf)
#pragma unroll
      for (int ks = 0; ks < 2; ++ks)
        a_[mf][ks] = fragld64(Ab, wm + 64 + mf * 16 + lr, ks, lq);
#pragma unroll
    for (int mf = 0; mf < 4; ++mf)
#pragma unroll
      for (int ks = 0; ks < 2; ++ks)
        acc[4 + mf][1] = __builtin_amdgcn_mfma_f32_16x16x32_bf16(
            a_[mf][ks], b1_[ks], acc[4 + mf][1], 0, 0, 0);
#pragma unroll
    for (int mf = 0; mf < 4; ++mf)
#pragma unroll
      for (int ks = 0; ks < 2; ++ks)
        acc[4 + mf][0] = __builtin_amdgcn_mfma_f32_16x16x32_bf16(
            a_[mf][ks], b0_[ks], acc[4 + mf][0], 0, 0, 0);

    __syncthreads();
    cur ^= 1;
  }

  const int rq = lq * 4;
  if (n0 < 1024) {  // Q: normal row-major into qkv (stride 3072)
#pragma unroll
    for (int mf = 0; mf < 8; ++mf)
#pragma unroll
      for (int nf2 = 0; nf2 < 2; ++nf2) {
        const int col = (int)n0 + wn + nf2 * 16 + lr;
#pragma unroll
        for (int r = 0; r < 4; ++r) {
          const long row = m0 + wm + mf * 16 + rq + r;
          Qout[row * 3072 + col] = f2bf(acc[mf][nf2][r]);
        }
      }
  } else if (n0 < 2048) {  // K -> fragment order
#pragma unroll
    for (int mf = 0; mf < 8; ++mf)
#pragma unroll
      for (int nf2 = 0; nf2 < 2; ++nf2) {
        const int cc = (int)n0 + wn + nf2 * 16 + lr - 1024;
        const int h = cc >> 6, d = cc & 63;
#pragma unroll
        for (int r = 0; r < 4; ++r) {
          const int row = (int)m0 + wm + mf * 16 + rq + r;
          const int b = row >> 11, t = row & 2047;
          const long base =
              ((long)((b * 16 + h) * 32 + (t >> 6)) * 8 + (d >> 5) * 4 +
               ((t >> 4) & 3)) * 512;
          KF[base + (((d >> 3) & 3) * 16 + (t & 15)) * 8 + (d & 7)] =
              f2bf(acc[mf][nf2][r]);
        }
      }
  } else {  // V -> fragment order
#pragma unroll
    for (int mf = 0; mf < 8; ++mf)
#pragma unroll
      for (int nf2 = 0; nf2 < 2; ++nf2) {
        const int cc = (int)n0 + wn + nf2 * 16 + lr - 2048;
        const int h = cc >> 6, d = cc & 63;
#pragma unroll
        for (int r = 0; r < 4; ++r) {
          const int row = (int)m0 + wm + mf * 16 + rq + r;
          const int b = row >> 11, t = row & 2047;
          const long base =
              ((long)((b * 16 + h) * 32 + (t >> 6)) * 8 + ((t >> 5) & 1) * 4 +
               (d >> 4)) * 512;
          VF[base + (((t >> 3) & 3) * 16 + (d & 15)) * 8 + (t & 7)] =
              f2bf(acc[mf][nf2][r]);
        }
      }
  }
}

// ---------------------------------------------------------------------------
// Flash attention v9.  Grid (T/128, B*H), block 256, (256,3): 3 blocks/CU.
// Each wave: 32 Q-rows.  S^T = K.Q^T via mfma(bk, aq) -> per-lane softmax.
// Ps: 32 rows x 64 u16, 16B-window XOR swizzle (wphys = wlog ^ (lr&7)).
// ---------------------------------------------------------------------------
__global__ __launch_bounds__(256, 3) void flash_attn(
    const u16* __restrict__ qkv, const u16* __restrict__ KF,
    const u16* __restrict__ VF, u16* __restrict__ cat) {
  const int T = 2048, LD = 3072;
  const float QSCALE = 0.18033688011112042f;  // log2e / 8
  const float EXPC = 4.3280851226677321f;     // 3 * log2e (static max)
  const int bh = blockIdx.y;
  const int b = bh >> 4, h = bh & 15;
  const int tid = threadIdx.x, wave = tid >> 6, lane = tid & 63;
  const int lr = lane & 15, lq = lane >> 4;

  __shared__ u16 Ps[4 * 32 * 64];  // per-wave 32 rows x 64 u16, swizzled
  u16* Pw = Ps + wave * 32 * 64;

  const u16* Qb = qkv + (long)(b * 2048) * LD + h * 64;
  const long fbase = (long)bh * 32 * 8 * 512;

  bf16x8 aq[2][2];
#pragma unroll
  for (int st = 0; st < 2; ++st) {
    int qrow = blockIdx.x * 128 + wave * 32 + st * 16 + lr;
#pragma unroll
    for (int kt = 0; kt < 2; ++kt) {
      u16x8 q = *(const u16x8*)(Qb + (long)qrow * LD + kt * 32 + lq * 8);
      bf16x8 t;
#pragma unroll
      for (int j = 0; j < 8; ++j) t[j] = (__bf16)(bf2f(q[j]) * QSCALE);
      aq[st][kt] = t;
    }
  }

  f32x4 o[2][4] = {};
  float lsum[2] = {0.0f, 0.0f};

  for (int jblk = 0; jblk < T / 64; ++jblk) {
    const u16* kf = KF + fbase + (long)jblk * 8 * 512;
    const u16* vf = VF + fbase + (long)jblk * 8 * 512;

    bf16x8 bk[2][4];
#pragma unroll
    for (int kt = 0; kt < 2; ++kt)
#pragma unroll
      for (int nt = 0; nt < 4; ++nt)
        bk[kt][nt] = *(const bf16x8*)(kf + (kt * 4 + nt) * 512 + lane * 8);

    f32x4 s[2][4] = {};
    __builtin_amdgcn_s_setprio(1);
#pragma unroll
    for (int st = 0; st < 2; ++st)
#pragma unroll
      for (int nt = 0; nt < 4; ++nt)
#pragma unroll
        for (int kt = 0; kt < 2; ++kt)
          s[st][nt] = __builtin_amdgcn_mfma_f32_16x16x32_bf16(
              bk[kt][nt], aq[st][kt], s[st][nt], 0, 0, 0);
    __builtin_amdgcn_s_setprio(0);

    bf16x8 bv[2][4];
#pragma unroll
    for (int kt = 0; kt < 2; ++kt)
#pragma unroll
      for (int nt = 0; nt < 4; ++nt)
        bv[kt][nt] = *(const bf16x8*)(vf + (kt * 4 + nt) * 512 + lane * 8);

#pragma unroll
    for (int st = 0; st < 2; ++st)
#pragma unroll
      for (int nt = 0; nt < 4; ++nt) {
        f32x4 p;
#pragma unroll
        for (int r = 0; r < 4; ++r) p[r] = EXP2F(s[st][nt][r] - EXPC);
        lsum[st] += (p[0] + p[1]) + (p[2] + p[3]);
        bf16x4 pk;
#pragma unroll
        for (int r = 0; r < 4; ++r) pk[r] = (__bf16)p[r];
        int wph = (nt * 2 + (lq >> 1)) ^ (lr & 7);
        *(bf16x4*)(Pw + (st * 16 + lr) * 64 + wph * 8 + (lq & 1) * 4) = pk;
      }

#pragma unroll
    for (int st = 0; st < 2; ++st)
#pragma unroll
      for (int kt = 0; kt < 2; ++kt) {
        bf16x8 ap = *(const bf16x8*)(
            Pw + (st * 16 + lr) * 64 + (((kt * 4 + lq) ^ (lr & 7)) * 8));
        __builtin_amdgcn_s_setprio(1);
#pragma unroll
        for (int nt = 0; nt < 4; ++nt)
          o[st][nt] = __builtin_amdgcn_mfma_f32_16x16x32_bf16(
              ap, bv[kt][nt], o[st][nt], 0, 0, 0);
        __builtin_amdgcn_s_setprio(0);
      }
  }

#pragma unroll
  for (int st = 0; st < 2; ++st) {
    lsum[st] += __shfl_xor(lsum[st], 16, 64);
    lsum[st] += __shfl_xor(lsum[st], 32, 64);
  }

  u16* ob = cat + (long)(b * 2048) * 1024 + h * 64;
#pragma unroll
  for (int st = 0; st < 2; ++st) {
    int trow = blockIdx.x * 128 + wave * 32 + st * 16 + lq * 4;
#pragma unroll
    for (int r = 0; r < 4; ++r) {
      float linv = 1.0f / __shfl(lsum[st], lq * 4 + r, 64);
#pragma unroll
      for (int nt = 0; nt < 4; ++nt)
        ob[(long)(trow + r) * 1024 + nt * 16 + lr] = f2bf(o[st][nt][r] * linv);
    }
  }
}

// ---------------------------------------------------------------------------
// out[row] = res[row] + LN(y[row]) * g + b.   y is bf16.
// ---------------------------------------------------------------------------
__global__ __launch_bounds__(256) void ln_residual(
    const u16* __restrict__ y, const void* __restrict__ res, int res_raw,
    const u16* __restrict__ g, const u16* __restrict__ bb,
    void* __restrict__ out, const int* __restrict__ flagp, int final_out) {
  const long row = blockIdx.x;
  const int tid = threadIdx.x, wave = tid >> 6, lane = tid & 63;
  u16x4 yv = *(const u16x4*)(y + row * 1024 + tid * 4);
  float yy[4];
#pragma unroll
  for (int j = 0; j < 4; ++j) yy[j] = bf2f(yv[j]);
  float s1 = yy[0] + yy[1] + yy[2] + yy[3];
  float s2 = yy[0] * yy[0] + yy[1] * yy[1] + yy[2] * yy[2] + yy[3] * yy[3];
#pragma unroll
  for (int off = 1; off < 64; off <<= 1) {
    s1 += __shfl_xor(s1, off, 64);
    s2 += __shfl_xor(s2, off, 64);
  }
  __shared__ float ws1[4], ws2[4];
  if (lane == 0) { ws1[wave] = s1; ws2[wave] = s2; }
  __syncthreads();
  float t1 = ws1[0] + ws1[1] + ws1[2] + ws1[3];
  float t2 = ws2[0] + ws2[1] + ws2[2] + ws2[3];
  float mu = t1 * (1.0f / 1024.0f);
  float var = t2 * (1.0f / 1024.0f) - mu * mu;
  float rstd = rsqrtf(var + 1e-5f);
  int i = tid * 4;
  bool f32in = res_raw && (*flagp);
  bool f32out = final_out && (*flagp);
#pragma unroll
  for (int j = 0; j < 4; ++j) {
    float rv = f32in ? ((const float*)res)[row * 1024 + i + j]
                     : bf2f(((const u16*)res)[row * 1024 + i + j]);
    float o = rv + (yy[j] - mu) * rstd * bf2f(g[i + j]) + bf2f(bb[i + j]);
    if (f32out)
      ((float*)out)[row * 1024 + i + j] = o;
    else
      ((u16*)out)[row * 1024 + i + j] = f2bf(o);
  }
}

// ---------------------------------------------------------------------------
extern "C" void kernel_launch(void* const* d_in, const int* in_sizes, int n_in,
                              void* d_out, int out_size, void* d_ws,
                              size_t ws_size, hipStream_t stream) {
  const void* x_raw = d_in[0];
  const void* Wq = d_in[1];
  const void* Wk = d_in[2];
  const void* Wv = d_in[3];
  const void* Wo = d_in[4];
  const void* bo = d_in[5];
  const void* ln1g = d_in[6];
  const void* ln1b = d_in[7];
  const void* W1 = d_in[8];
  const void* b1 = d_in[9];
  const void* W2 = d_in[10];
  const void* b2 = d_in[11];
  const void* ln2g = d_in[12];
  const void* ln2b = d_in[13];

  char* ws = (char*)d_ws;
  // Liveness map (re-verified for fused kv_frag):
  //  [0,48M): qkv (Q cols only; K/V cols unused) -> mha[0,16M) -> h1[0,64M)
  //  [48,64M): VF (written by gemm_qkv, read by flash, then dead)
  //  [64,80M): KF (same lifetime) -> ff[64,80M)
  //  [80,96M): xb (dead after gemm_qkv) -> cat (dead after Wo gemm) -> x1
  //  [96M...): weights / vecs / flag
  u16* qkv = (u16*)(ws + 0);              // [8192,3072] (Q valid)
  u16* mha = (u16*)(ws + 0);              // [8192,1024] bf16
  u16* h1 = (u16*)(ws + 0);               // [8192,4096] bf16
  u16* VF = (u16*)(ws + 50331648);        // frag-order V (16M)
  u16* KF = (u16*)(ws + 67108864);        // frag-order K (16M)
  u16* ff = (u16*)(ws + 67108864);        // [8192,1024] bf16
  u16* xb = (u16*)(ws + 83886080);        // bf16 x
  u16* cat = (u16*)(ws + 83886080);       // [8192,1024] after xb dead
  u16* x1 = (u16*)(ws + 83886080);        // [8192,1024] after cat dead
  u16* wqkvt = (u16*)(ws + 100663296);    // [3072,1024]
  u16* wot = (u16*)(ws + 106954752);      // [1024,1024]
  u16* w1t = (u16*)(ws + 109051904);      // [4096,1024]
  u16* w2t = (u16*)(ws + 117440512);      // [1024,4096]
  u16* vecs = (u16*)(ws + 125829120);     // packed bias/gain vectors
  int* flag = (int*)(ws + 125853696);     // dtype flag (1 = fp32)

  const u16* v_bo = vecs + 0;
  const u16* v_l1g = vecs + 1024;
  const u16* v_l1b = vecs + 2048;
  const u16* v_b1 = vecs + 3072;
  const u16* v_b2 = vecs + 7168;
  const u16* v_l2g = vecs + 8192;
  const u16* v_l2b = vecs + 9216;

  detect_dtype<<<1, 256, 0, stream>>>((const u16*)x_raw, flag);
  // one launch for all flag-dependent setup (cvt_copy + vecs + 4 transposes)
  setup_all<<<20487, 256, 0, stream>>>(
      x_raw, xb, bo, ln1g, ln1b, b1, b2, ln2g, ln2b, vecs,
      Wq, Wk, Wv, wqkvt, Wo, wot, W1, w1t, W2, w2t, flag);

  // qkv = xb @ Wqkv, with K/V written directly in fragment order
  gemm_qkv<<<768, 512, 0, stream>>>(xb, wqkvt, qkv, KF, VF);
  // cat = attention
  flash_attn<<<dim3(16, 64), 256, 0, stream>>>(qkv, KF, VF, cat);
  // mha = cat @ Wo + bo (gemm2ph BN=128; grid 256, measured-best)
  gemm2ph<3, 128><<<256, 512, 0, stream>>>(cat, wot, v_bo, mha, 8192, 1024, 1024);
  // x1 = x_raw + LN(mha)
  ln_residual<<<8192, 256, 0, stream>>>(mha, x_raw, 1, v_l1g, v_l1b, x1, flag, 0);
  // h1 = gelu(x1 @ W1 + b1) (gemm2ph BN=256; 512 wgs, measured-best)
  gemm2ph<2, 256><<<512, 512, 0, stream>>>(x1, w1t, v_b1, h1, 8192, 4096, 1024);
  // ff = h1 @ W2 + b2 (gemm2ph BN=128; grid 256, measured-best)
  gemm2ph<3, 128><<<256, 512, 0, stream>>>(h1, w2t, v_b2, ff, 8192, 1024, 4096);
  // out = x1 + LN(ff)
  ln_residual<<<8192, 256, 0, stream>>>(ff, x1, 0, v_l2g, v_l2b, d_out, flag, 1);
}